// Round 2
// baseline (1410.465 us; speedup 1.0000x reference)
//
#include <hip/hip_runtime.h>
#include <hip/hip_fp16.h>

#define EMB 2048
#define NH 16
#define HD 128
#define BATCH 4
#define SEQ 2048
#define MROWS (BATCH * SEQ)   // 8192

typedef __attribute__((ext_vector_type(8))) _Float16 f16x8;
typedef __attribute__((ext_vector_type(4))) float f32x4;

typedef __attribute__((address_space(3))) unsigned int lds_u32_t;
typedef const __attribute__((address_space(1))) unsigned int glb_u32_t;

__device__ __forceinline__ void async_copy16(void* lds, const void* g) {
    __builtin_amdgcn_global_load_lds((glb_u32_t*)g, (lds_u32_t*)lds, 16, 0, 0);
}

// ---------------- fp32 -> fp16 convert ----------------
__global__ void cvt_f32_f16(const float* __restrict__ in, __half* __restrict__ out, int n4) {
    int i = blockIdx.x * 256 + threadIdx.x;
    if (i < n4) {
        float4 v = ((const float4*)in)[i];
        __half2 a, b;
        a.x = __float2half(v.x); a.y = __float2half(v.y);
        b.x = __float2half(v.z); b.y = __float2half(v.w);
        ((__half2*)out)[2 * i]     = a;
        ((__half2*)out)[2 * i + 1] = b;
    }
}

// ---------------- shared GEMM mainloop: C(128x128) = A * B^T, K = 2048 ----------------
__device__ __forceinline__ void gemm_mainloop(const __half* __restrict__ A,
                                              const __half* __restrict__ B,
                                              int m0, int n0,
                                              short* sA, short* sB,
                                              f32x4 acc[4][4]) {
    const int tid  = threadIdx.x;
    const int wave = tid >> 6;
    const int lane = tid & 63;
    const int wr = wave >> 1, wc = wave & 1;
    const int frow = lane & 15;
    const int fk   = (lane >> 4) * 8;
    const int r0 = tid >> 2;
    const int cb = (tid & 3) * 16;
    const char* gA = (const char*)A;
    const char* gB = (const char*)B;
    char* lA = (char*)sA;
    char* lB = (char*)sB;
    const int off0 = wave * 1024;
    const int off1 = 4096 + wave * 1024;

    for (int kt = 0; kt < EMB; kt += 32) {
        size_t kb = (size_t)kt * 2;
        async_copy16(lA + off0, gA + ((size_t)(m0 + r0) * EMB) * 2 + kb + cb);
        async_copy16(lA + off1, gA + ((size_t)(m0 + 64 + r0) * EMB) * 2 + kb + cb);
        async_copy16(lB + off0, gB + ((size_t)(n0 + r0) * EMB) * 2 + kb + cb);
        async_copy16(lB + off1, gB + ((size_t)(n0 + 64 + r0) * EMB) * 2 + kb + cb);
        __syncthreads();

        f16x8 af[4], bf[4];
#pragma unroll
        for (int i = 0; i < 4; i++)
            af[i] = *(const f16x8*)&sA[(wr * 64 + i * 16 + frow) * 32 + fk];
#pragma unroll
        for (int i = 0; i < 4; i++)
            bf[i] = *(const f16x8*)&sB[(wc * 64 + i * 16 + frow) * 32 + fk];
#pragma unroll
        for (int mi = 0; mi < 4; mi++)
#pragma unroll
            for (int ni = 0; ni < 4; ni++)
                acc[mi][ni] = __builtin_amdgcn_mfma_f32_16x16x32_f16(af[mi], bf[ni], acc[mi][ni], 0, 0, 0);
        __syncthreads();
    }
}

// ---------------- QKV projection + RoPE, writes (B,H,S,D) fp16 ----------------
__global__ __launch_bounds__(256) void gemm_qkv(const __half* __restrict__ X,
                                                const __half* __restrict__ Wq,
                                                const __half* __restrict__ Wk,
                                                const __half* __restrict__ Wv,
                                                __half* __restrict__ Q,
                                                __half* __restrict__ K,
                                                __half* __restrict__ V) {
    __shared__ short sA[128 * 32];
    __shared__ short sB[128 * 32];
    const int mblk = blockIdx.x;
    const int nb   = blockIdx.y;
    const int wsel = nb >> 4;
    const int nloc = (nb & 15) * 128;
    const __half* W = (wsel == 0) ? Wq : ((wsel == 1) ? Wk : Wv);

    f32x4 z = {0.f, 0.f, 0.f, 0.f};
    f32x4 acc[4][4];
#pragma unroll
    for (int i = 0; i < 4; i++)
#pragma unroll
        for (int j = 0; j < 4; j++) acc[i][j] = z;

    gemm_mainloop(X, W, mblk * 128, nloc, sA, sB, acc);

    const int lane = threadIdx.x & 63;
    const int wave = threadIdx.x >> 6;
    const int wr = wave >> 1, wc = wave & 1;
    const int q4 = lane >> 4;
    __half* Obuf = (wsel == 0) ? Q : ((wsel == 1) ? K : V);
    const bool rope = (wsel < 2);

#pragma unroll
    for (int ni = 0; ni < 4; ni++) {
        int n = nloc + wc * 64 + ni * 16 + (lane & 15);
        int h = n >> 7, d = n & 127;
        float invf = rope ? __expf(-((float)(d & ~1)) * (9.210340371976184f / 128.0f)) : 0.f;
#pragma unroll
        for (int mi = 0; mi < 4; mi++) {
#pragma unroll
            for (int r = 0; r < 4; r++) {
                int m = mblk * 128 + wr * 64 + mi * 16 + q4 * 4 + r;
                int b = m >> 11, s = m & 2047;
                float v = acc[mi][ni][r];
                float res;
                if (rope) {
                    float p = __shfl_xor(v, 1);
                    float ang = (float)s * invf;
                    float sn, cs;
                    __sincosf(ang, &sn, &cs);
                    if ((lane & 1) == 0) res = v * cs - p * sn;
                    else                 res = v * cs + p * sn;
                } else {
                    res = v;
                }
                float pr = __shfl_xor(res, 1);
                if ((lane & 1) == 0) {
                    __half2 hv;
                    hv.x = __float2half(res);
                    hv.y = __float2half(pr);
                    size_t off = ((size_t)(b * NH + h) * SEQ + s) * HD + d;
                    *(__half2*)(Obuf + off) = hv;
                }
            }
        }
    }
}

// ---------------- V transpose: V[bh][s][d] -> Vt[bh][d][s] ----------------
__global__ __launch_bounds__(256) void transpose_v(const __half* __restrict__ V,
                                                   __half* __restrict__ Vt) {
    __shared__ short t[64 * 65];
    const int st = blockIdx.x & 31;
    const int dt = (blockIdx.x >> 5) & 1;
    const int bh = blockIdx.y;
    const int tid = threadIdx.x;
    const __half* Vh = V + (size_t)bh * SEQ * HD;
    __half* Vo = Vt + (size_t)bh * SEQ * HD;
#pragma unroll
    for (int k = 0; k < 2; k++) {
        int id = k * 256 + tid;
        int r = id >> 3, c8 = id & 7;
        f16x8 v = *(const f16x8*)(Vh + (size_t)(st * 64 + r) * HD + dt * 64 + c8 * 8);
#pragma unroll
        for (int e = 0; e < 8; e++) t[r * 65 + c8 * 8 + e] = ((short*)&v)[e];
    }
    __syncthreads();
#pragma unroll
    for (int k = 0; k < 2; k++) {
        int id = k * 256 + tid;
        int dr = id >> 3, sc8 = id & 7;
        f16x8 v;
#pragma unroll
        for (int e = 0; e < 8; e++) ((short*)&v)[e] = t[(sc8 * 8 + e) * 65 + dr];
        *(f16x8*)(Vo + (size_t)(dt * 64 + dr) * SEQ + st * 64 + sc8 * 8) = v;
    }
}

// ---------------- causal flash attention v2 ----------------
// LDS: two unpadded 128x128 fp16 tiles (64 KB total -> 2 blocks/CU).
// XOR chunk-swizzle (chunk ^ (row&15)) applied on the GLOBAL fetch side so
// pitch-128 b128 reads are phase-conflict-free.
__global__ __launch_bounds__(256, 2) void attn_kernel(const __half* __restrict__ Q,
                                                      const __half* __restrict__ K,
                                                      const __half* __restrict__ Vt,
                                                      __half* __restrict__ CTX) {
    __shared__ short sKP[128 * 128];   // K tile (swizzled); reused as P tile
    __shared__ short sVT[128 * 128];   // V^T tile (swizzled)
    const int qt = 15 - blockIdx.x;    // heavy blocks dispatch first
    const int bh = blockIdx.y;
    const int b = bh >> 4, h = bh & 15;
    const int tid = threadIdx.x;
    const int wave = tid >> 6, lane = tid & 63;
    const int fr = lane & 15, q4 = lane >> 4;
    const size_t headoff = (size_t)bh * SEQ * HD;
    const __half* Qh = Q + headoff;
    const __half* Kh = K + headoff;
    const __half* Vth = Vt + headoff;  // [d][s]
    char* sKc = (char*)sKP;
    char* sVc = (char*)sVT;

    // Q fragments in registers, 1/sqrt(HD) folded in
    f16x8 qf[2][4];
#pragma unroll
    for (int mi = 0; mi < 2; mi++)
#pragma unroll
        for (int ds = 0; ds < 4; ds++) {
            qf[mi][ds] = *(const f16x8*)(Qh + (size_t)(qt * 128 + wave * 32 + mi * 16 + fr) * HD + ds * 32 + q4 * 8);
            qf[mi][ds] = qf[mi][ds] * (_Float16)0.08838834764831845f;
        }

    f32x4 z = {0.f, 0.f, 0.f, 0.f};
    f32x4 accO[2][8];
#pragma unroll
    for (int i = 0; i < 2; i++)
#pragma unroll
        for (int j = 0; j < 8; j++) accO[i][j] = z;
    float mrow[2][4], lrow[2][4];
#pragma unroll
    for (int i = 0; i < 2; i++)
#pragma unroll
        for (int r = 0; r < 4; r++) { mrow[i][r] = -INFINITY; lrow[i][r] = 0.f; }

    for (int kt = 0; kt <= qt; kt++) {
        // ---- stage K tile via async (swizzled chunks) ----
#pragma unroll
        for (int j = 0; j < 8; j++) {
            int id = j * 256 + tid;
            int row = id >> 4;
            int gc = (id & 15) ^ (row & 15);
            async_copy16(sKc + id * 16, Kh + (size_t)(kt * 128 + row) * HD + gc * 8);
        }
        // ---- stage V^T tile via async (swizzled chunks) ----
#pragma unroll
        for (int j = 0; j < 8; j++) {
            int id = j * 256 + tid;
            int d = id >> 4;
            int gc = (id & 15) ^ (d & 15);
            async_copy16(sVc + id * 16, Vth + (size_t)d * SEQ + kt * 128 + gc * 8);
        }
        __syncthreads();   // barrier 1: async drained, tiles visible

        // ---- S = Q K^T ----
        f32x4 accS[2][8];
#pragma unroll
        for (int i = 0; i < 2; i++)
#pragma unroll
            for (int j = 0; j < 8; j++) accS[i][j] = z;
#pragma unroll
        for (int ds = 0; ds < 4; ds++) {
            f16x8 kf[8];
#pragma unroll
            for (int ni = 0; ni < 8; ni++)
                kf[ni] = *(const f16x8*)&sKP[(ni * 16 + fr) * 128 + (((ds * 4 + q4) ^ fr) * 8)];
#pragma unroll
            for (int mi = 0; mi < 2; mi++)
#pragma unroll
                for (int ni = 0; ni < 8; ni++)
                    accS[mi][ni] = __builtin_amdgcn_mfma_f32_16x16x32_f16(qf[mi][ds], kf[ni], accS[mi][ni], 0, 0, 0);
        }

        // ---- causal mask: diagonal tile only ----
        if (kt == qt) {
#pragma unroll
            for (int mi = 0; mi < 2; mi++)
#pragma unroll
                for (int r = 0; r < 4; r++) {
                    int qrow = wave * 32 + mi * 16 + q4 * 4 + r;   // within tile
#pragma unroll
                    for (int ni = 0; ni < 8; ni++) {
                        int kcol = ni * 16 + fr;
                        if (kcol > qrow) accS[mi][ni][r] = -INFINITY;
                    }
                }
        }

        // ---- online softmax (scale already folded into Q) ----
#pragma unroll
        for (int mi = 0; mi < 2; mi++) {
#pragma unroll
            for (int r = 0; r < 4; r++) {
                float mold = mrow[mi][r];
                float mx = mold;
#pragma unroll
                for (int ni = 0; ni < 8; ni++) mx = fmaxf(mx, accS[mi][ni][r]);
#pragma unroll
                for (int off = 1; off < 16; off <<= 1)
                    mx = fmaxf(mx, __shfl_xor(mx, off));
                float alpha = __expf(mold - mx);
                mrow[mi][r] = mx;
                float rs = 0.f;
#pragma unroll
                for (int ni = 0; ni < 8; ni++) {
                    float p = __expf(accS[mi][ni][r] - mx);
                    rs += p;
                    accS[mi][ni][r] = p;
                }
#pragma unroll
                for (int off = 1; off < 16; off <<= 1)
                    rs += __shfl_xor(rs, off);
                lrow[mi][r] = lrow[mi][r] * alpha + rs;
#pragma unroll
                for (int di = 0; di < 8; di++)
                    accO[mi][di][r] *= alpha;
            }
        }

        __syncthreads();   // barrier 2: all waves done reading K before P overwrite

        // ---- write P into sKP (wave-private rows, swizzled) ----
#pragma unroll
        for (int mi = 0; mi < 2; mi++)
#pragma unroll
            for (int ni = 0; ni < 8; ni++)
#pragma unroll
                for (int r = 0; r < 4; r++) {
                    float p = accS[mi][ni][r];
                    float pp = __shfl_xor(p, 1);
                    if ((lane & 1) == 0) {
                        int row = wave * 32 + mi * 16 + q4 * 4 + r;
                        int col = ni * 16 + fr;             // even
                        int xc = (col >> 3) ^ (q4 * 4 + r); // row&15 = q4*4+r
                        __half2 h2;
                        h2.x = __float2half(p);
                        h2.y = __float2half(pp);
                        *(__half2*)&sKP[row * 128 + xc * 8 + (col & 7)] = h2;
                    }
                }

        // ---- O += P V (P wave-private; V^T from LDS) ----
#pragma unroll
        for (int ns = 0; ns < 4; ns++) {
            f16x8 pf[2], vf[8];
#pragma unroll
            for (int mi = 0; mi < 2; mi++)
                pf[mi] = *(const f16x8*)&sKP[(wave * 32 + mi * 16 + fr) * 128 + (((ns * 4 + q4) ^ fr) * 8)];
#pragma unroll
            for (int di = 0; di < 8; di++)
                vf[di] = *(const f16x8*)&sVT[(di * 16 + fr) * 128 + (((ns * 4 + q4) ^ fr) * 8)];
#pragma unroll
            for (int mi = 0; mi < 2; mi++)
#pragma unroll
                for (int di = 0; di < 8; di++)
                    accO[mi][di] = __builtin_amdgcn_mfma_f32_16x16x32_f16(pf[mi], vf[di], accO[mi][di], 0, 0, 0);
        }
        __syncthreads();   // barrier 3: P/V reads done before next staging
    }

    // ---- epilogue ----
    float linv[2][4];
#pragma unroll
    for (int mi = 0; mi < 2; mi++)
#pragma unroll
        for (int r = 0; r < 4; r++) linv[mi][r] = 1.f / lrow[mi][r];

#pragma unroll
    for (int mi = 0; mi < 2; mi++)
#pragma unroll
        for (int di = 0; di < 8; di++)
#pragma unroll
            for (int r = 0; r < 4; r++) {
                float o = accO[mi][di][r] * linv[mi][r];
                float po = __shfl_xor(o, 1);
                if ((lane & 1) == 0) {
                    int srow = qt * 128 + wave * 32 + mi * 16 + q4 * 4 + r;
                    int d = di * 16 + fr;  // even
                    size_t off = ((size_t)(b * SEQ + srow)) * EMB + h * HD + d;
                    __half2 h2;
                    h2.x = __float2half(o);
                    h2.y = __float2half(po);
                    *(__half2*)&CTX[off] = h2;
                }
            }
}

// ---------------- output projection: out(fp32) = CTX * Wo^T ----------------
__global__ __launch_bounds__(256) void gemm_out(const __half* __restrict__ CTX,
                                                const __half* __restrict__ Wo,
                                                float* __restrict__ out) {
    __shared__ short sA[128 * 32];
    __shared__ short sB[128 * 32];
    f32x4 z = {0.f, 0.f, 0.f, 0.f};
    f32x4 acc[4][4];
#pragma unroll
    for (int i = 0; i < 4; i++)
#pragma unroll
        for (int j = 0; j < 4; j++) acc[i][j] = z;

    gemm_mainloop(CTX, Wo, blockIdx.x * 128, blockIdx.y * 128, sA, sB, acc);

    const int lane = threadIdx.x & 63;
    const int wave = threadIdx.x >> 6;
    const int wr = wave >> 1, wc = wave & 1;
    const int q4 = lane >> 4;
#pragma unroll
    for (int mi = 0; mi < 4; mi++)
#pragma unroll
        for (int ni = 0; ni < 4; ni++)
#pragma unroll
            for (int r = 0; r < 4; r++) {
                int m = blockIdx.x * 128 + wr * 64 + mi * 16 + q4 * 4 + r;
                int n = blockIdx.y * 128 + wc * 64 + ni * 16 + (lane & 15);
                out[(size_t)m * EMB + n] = acc[mi][ni][r];
            }
}

extern "C" void kernel_launch(void* const* d_in, const int* in_sizes, int n_in,
                              void* d_out, int out_size, void* d_ws, size_t ws_size,
                              hipStream_t stream) {
    const float* x  = (const float*)d_in[0];
    const float* Wq = (const float*)d_in[1];
    const float* Wk = (const float*)d_in[2];
    const float* Wv = (const float*)d_in[3];
    const float* Wo = (const float*)d_in[4];
    float* out = (float*)d_out;

    char* ws = (char*)d_ws;
    size_t off = 0;
    const size_t QKV_ELEMS = (size_t)MROWS * EMB;   // 16777216
    __half* Xh  = (__half*)(ws + off); off += QKV_ELEMS * 2;          // reused as CTX
    __half* Wqh = (__half*)(ws + off); off += (size_t)EMB * EMB * 2;
    __half* Wkh = (__half*)(ws + off); off += (size_t)EMB * EMB * 2;
    __half* Wvh = (__half*)(ws + off); off += (size_t)EMB * EMB * 2;
    __half* Woh = (__half*)(ws + off); off += (size_t)EMB * EMB * 2;
    __half* Qb  = (__half*)(ws + off); off += QKV_ELEMS * 2;
    __half* Kb  = (__half*)(ws + off); off += QKV_ELEMS * 2;
    __half* Vb  = (__half*)(ws + off); off += QKV_ELEMS * 2;
    __half* Vtb = (__half*)(ws + off); off += QKV_ELEMS * 2;
    __half* Cb  = Xh;   // X dead after gemm_qkv

    cvt_f32_f16<<<16384, 256, 0, stream>>>(x,  Xh,  4194304);
    cvt_f32_f16<<<4096,  256, 0, stream>>>(Wq, Wqh, 1048576);
    cvt_f32_f16<<<4096,  256, 0, stream>>>(Wk, Wkh, 1048576);
    cvt_f32_f16<<<4096,  256, 0, stream>>>(Wv, Wvh, 1048576);
    cvt_f32_f16<<<4096,  256, 0, stream>>>(Wo, Woh, 1048576);

    gemm_qkv<<<dim3(64, 48), 256, 0, stream>>>(Xh, Wqh, Wkh, Wvh, Qb, Kb, Vb);
    transpose_v<<<dim3(64, 64), 256, 0, stream>>>(Vb, Vtb);
    attn_kernel<<<dim3(16, 64), 256, 0, stream>>>(Qb, Kb, Vtb, Cb);
    gemm_out<<<dim3(64, 16), 256, 0, stream>>>(Cb, Woh, out);
}

// Round 3
// 937.933 us; speedup vs baseline: 1.5038x; 1.5038x over previous
//
#include <hip/hip_runtime.h>
#include <hip/hip_fp16.h>

#define EMB 2048
#define NH 16
#define HD 128
#define BATCH 4
#define SEQ 2048
#define MROWS (BATCH * SEQ)   // 8192

typedef __attribute__((ext_vector_type(8))) _Float16 f16x8;
typedef __attribute__((ext_vector_type(4))) float f32x4;

typedef __attribute__((address_space(3))) unsigned int lds_u32_t;
typedef const __attribute__((address_space(1))) unsigned int glb_u32_t;

__device__ __forceinline__ void async_copy16(void* lds, const void* g) {
    __builtin_amdgcn_global_load_lds((glb_u32_t*)g, (lds_u32_t*)lds, 16, 0, 0);
}

// ---------------- fp32 -> fp16 convert ----------------
__global__ void cvt_f32_f16(const float* __restrict__ in, __half* __restrict__ out, int n4) {
    int i = blockIdx.x * 256 + threadIdx.x;
    if (i < n4) {
        float4 v = ((const float4*)in)[i];
        __half2 a, b;
        a.x = __float2half(v.x); a.y = __float2half(v.y);
        b.x = __float2half(v.z); b.y = __float2half(v.w);
        ((__half2*)out)[2 * i]     = a;
        ((__half2*)out)[2 * i + 1] = b;
    }
}

// ---------------- shared GEMM mainloop: C(128x128) = A * B^T, K = 2048 ----------------
__device__ __forceinline__ void gemm_mainloop(const __half* __restrict__ A,
                                              const __half* __restrict__ B,
                                              int m0, int n0,
                                              short* sA, short* sB,
                                              f32x4 acc[4][4]) {
    const int tid  = threadIdx.x;
    const int wave = tid >> 6;
    const int lane = tid & 63;
    const int wr = wave >> 1, wc = wave & 1;
    const int frow = lane & 15;
    const int fk   = (lane >> 4) * 8;
    const int r0 = tid >> 2;
    const int cb = (tid & 3) * 16;
    const char* gA = (const char*)A;
    const char* gB = (const char*)B;
    char* lA = (char*)sA;
    char* lB = (char*)sB;
    const int off0 = wave * 1024;
    const int off1 = 4096 + wave * 1024;

    for (int kt = 0; kt < EMB; kt += 32) {
        size_t kb = (size_t)kt * 2;
        async_copy16(lA + off0, gA + ((size_t)(m0 + r0) * EMB) * 2 + kb + cb);
        async_copy16(lA + off1, gA + ((size_t)(m0 + 64 + r0) * EMB) * 2 + kb + cb);
        async_copy16(lB + off0, gB + ((size_t)(n0 + r0) * EMB) * 2 + kb + cb);
        async_copy16(lB + off1, gB + ((size_t)(n0 + 64 + r0) * EMB) * 2 + kb + cb);
        __syncthreads();

        f16x8 af[4], bf[4];
#pragma unroll
        for (int i = 0; i < 4; i++)
            af[i] = *(const f16x8*)&sA[(wr * 64 + i * 16 + frow) * 32 + fk];
#pragma unroll
        for (int i = 0; i < 4; i++)
            bf[i] = *(const f16x8*)&sB[(wc * 64 + i * 16 + frow) * 32 + fk];
#pragma unroll
        for (int mi = 0; mi < 4; mi++)
#pragma unroll
            for (int ni = 0; ni < 4; ni++)
                acc[mi][ni] = __builtin_amdgcn_mfma_f32_16x16x32_f16(af[mi], bf[ni], acc[mi][ni], 0, 0, 0);
        __syncthreads();
    }
}

// ---------------- QKV projection + RoPE, writes (B,H,S,D) fp16 ----------------
__global__ __launch_bounds__(256) void gemm_qkv(const __half* __restrict__ X,
                                                const __half* __restrict__ Wq,
                                                const __half* __restrict__ Wk,
                                                const __half* __restrict__ Wv,
                                                __half* __restrict__ Q,
                                                __half* __restrict__ K,
                                                __half* __restrict__ V) {
    __shared__ short sA[128 * 32];
    __shared__ short sB[128 * 32];
    const int mblk = blockIdx.x;
    const int nb   = blockIdx.y;
    const int wsel = nb >> 4;
    const int nloc = (nb & 15) * 128;
    const __half* W = (wsel == 0) ? Wq : ((wsel == 1) ? Wk : Wv);

    f32x4 z = {0.f, 0.f, 0.f, 0.f};
    f32x4 acc[4][4];
#pragma unroll
    for (int i = 0; i < 4; i++)
#pragma unroll
        for (int j = 0; j < 4; j++) acc[i][j] = z;

    gemm_mainloop(X, W, mblk * 128, nloc, sA, sB, acc);

    const int lane = threadIdx.x & 63;
    const int wave = threadIdx.x >> 6;
    const int wr = wave >> 1, wc = wave & 1;
    const int q4 = lane >> 4;
    __half* Obuf = (wsel == 0) ? Q : ((wsel == 1) ? K : V);
    const bool rope = (wsel < 2);

#pragma unroll
    for (int ni = 0; ni < 4; ni++) {
        int n = nloc + wc * 64 + ni * 16 + (lane & 15);
        int h = n >> 7, d = n & 127;
        float invf = rope ? __expf(-((float)(d & ~1)) * (9.210340371976184f / 128.0f)) : 0.f;
#pragma unroll
        for (int mi = 0; mi < 4; mi++) {
#pragma unroll
            for (int r = 0; r < 4; r++) {
                int m = mblk * 128 + wr * 64 + mi * 16 + q4 * 4 + r;
                int b = m >> 11, s = m & 2047;
                float v = acc[mi][ni][r];
                float res;
                if (rope) {
                    float p = __shfl_xor(v, 1);
                    float ang = (float)s * invf;
                    float sn, cs;
                    __sincosf(ang, &sn, &cs);
                    if ((lane & 1) == 0) res = v * cs - p * sn;
                    else                 res = v * cs + p * sn;
                } else {
                    res = v;
                }
                float pr = __shfl_xor(res, 1);
                if ((lane & 1) == 0) {
                    __half2 hv;
                    hv.x = __float2half(res);
                    hv.y = __float2half(pr);
                    size_t off = ((size_t)(b * NH + h) * SEQ + s) * HD + d;
                    *(__half2*)(Obuf + off) = hv;
                }
            }
        }
    }
}

// ---------------- V transpose: V[bh][s][d] -> Vt[bh][d][s] ----------------
__global__ __launch_bounds__(256) void transpose_v(const __half* __restrict__ V,
                                                   __half* __restrict__ Vt) {
    __shared__ short t[64 * 65];
    const int st = blockIdx.x & 31;
    const int dt = (blockIdx.x >> 5) & 1;
    const int bh = blockIdx.y;
    const int tid = threadIdx.x;
    const __half* Vh = V + (size_t)bh * SEQ * HD;
    __half* Vo = Vt + (size_t)bh * SEQ * HD;
#pragma unroll
    for (int k = 0; k < 2; k++) {
        int id = k * 256 + tid;
        int r = id >> 3, c8 = id & 7;
        f16x8 v = *(const f16x8*)(Vh + (size_t)(st * 64 + r) * HD + dt * 64 + c8 * 8);
#pragma unroll
        for (int e = 0; e < 8; e++) t[r * 65 + c8 * 8 + e] = ((short*)&v)[e];
    }
    __syncthreads();
#pragma unroll
    for (int k = 0; k < 2; k++) {
        int id = k * 256 + tid;
        int dr = id >> 3, sc8 = id & 7;
        f16x8 v;
#pragma unroll
        for (int e = 0; e < 8; e++) ((short*)&v)[e] = t[(sc8 * 8 + e) * 65 + dr];
        *(f16x8*)(Vo + (size_t)(dt * 64 + dr) * SEQ + st * 64 + sc8 * 8) = v;
    }
}

// ---------------- causal flash attention v3 ----------------
// BQ=64 (16 rows/wave), BK=64. LDS 40KB: sK 16KB + sV 16KB + sP 8KB.
// 3 blocks/CU (launch_bounds 256,3) + register prefetch pipeline.
// Swizzled unpadded tiles (conflict-free); P transpose via wave-private
// scratch (no barrier). 2 barriers per K-tile iteration.
__global__ __launch_bounds__(256, 3) void attn_kernel(const __half* __restrict__ Q,
                                                      const __half* __restrict__ K,
                                                      const __half* __restrict__ Vt,
                                                      __half* __restrict__ CTX) {
    __shared__ short sK[64 * 128];      // K tile: 64 keys x 128 d, 16-chunk swizzle
    __shared__ short sV[128 * 64];      // V^T tile: 128 d x 64 keys, 8-chunk swizzle
    __shared__ short sP[4][16 * 64];    // per-wave P scratch
    const int qt = 31 - (int)blockIdx.x;   // 0..31, heavy blocks first
    const int bh = blockIdx.y;
    const int b = bh >> 4, h = bh & 15;
    const int tid = threadIdx.x;
    const int wave = tid >> 6, lane = tid & 63;
    const int fr = lane & 15, q4 = lane >> 4;
    const size_t headoff = (size_t)bh * SEQ * HD;
    const __half* Qh = Q + headoff;
    const __half* Kh = K + headoff;
    const __half* Vth = Vt + headoff;   // [d][s]
    short* sPw = &sP[wave][0];

    // Q fragments (wave rows qt*64 + wave*16 + fr), scale folded
    f16x8 qf[4];
#pragma unroll
    for (int ds = 0; ds < 4; ds++) {
        qf[ds] = *(const f16x8*)(Qh + (size_t)(qt * 64 + wave * 16 + fr) * HD + ds * 32 + q4 * 8);
        qf[ds] = qf[ds] * (_Float16)0.08838834764831845f;
    }

    f32x4 z = {0.f, 0.f, 0.f, 0.f};
    f32x4 accO[8];
#pragma unroll
    for (int i = 0; i < 8; i++) accO[i] = z;
    float mrow[4], lrow[4];
#pragma unroll
    for (int r = 0; r < 4; r++) { mrow[r] = -INFINITY; lrow[r] = 0.f; }

    const int nk = qt + 1;

    // prefetch registers
    f16x8 kpre[4], vpre[4];
    {
        // tile 0
#pragma unroll
        for (int j = 0; j < 4; j++) {
            int id = j * 256 + tid;
            int row = id >> 4, c = id & 15;
            kpre[j] = *(const f16x8*)(Kh + (size_t)row * HD + c * 8);
        }
#pragma unroll
        for (int j = 0; j < 4; j++) {
            int id = j * 256 + tid;
            int d = id >> 3, c = id & 7;
            vpre[j] = *(const f16x8*)(Vth + (size_t)d * SEQ + c * 8);
        }
    }

    for (int kt = 0; kt < nk; kt++) {
        __syncthreads();   // barrier A: previous compute done reading sK/sV
        // ---- VGPR -> LDS (swizzled) ----
#pragma unroll
        for (int j = 0; j < 4; j++) {
            int id = j * 256 + tid;
            int row = id >> 4, c = id & 15;
            *(f16x8*)&sK[row * 128 + ((c ^ (row & 15)) * 8)] = kpre[j];
        }
#pragma unroll
        for (int j = 0; j < 4; j++) {
            int id = j * 256 + tid;
            int d = id >> 3, c = id & 7;
            *(f16x8*)&sV[d * 64 + ((c ^ (d & 7)) * 8)] = vpre[j];
        }
        __syncthreads();   // barrier B: tiles visible

        // ---- issue next tile's global loads (overlap with compute) ----
        if (kt + 1 < nk) {
            int kbase = (kt + 1) * 64;
#pragma unroll
            for (int j = 0; j < 4; j++) {
                int id = j * 256 + tid;
                int row = id >> 4, c = id & 15;
                kpre[j] = *(const f16x8*)(Kh + (size_t)(kbase + row) * HD + c * 8);
            }
#pragma unroll
            for (int j = 0; j < 4; j++) {
                int id = j * 256 + tid;
                int d = id >> 3, c = id & 7;
                vpre[j] = *(const f16x8*)(Vth + (size_t)d * SEQ + kbase + c * 8);
            }
        }

        // ---- S = Q K^T (16 rows x 64 cols per wave) ----
        f32x4 accS[4];
#pragma unroll
        for (int i = 0; i < 4; i++) accS[i] = z;
#pragma unroll
        for (int ds = 0; ds < 4; ds++) {
            f16x8 kf[4];
#pragma unroll
            for (int ni = 0; ni < 4; ni++)
                kf[ni] = *(const f16x8*)&sK[(ni * 16 + fr) * 128 + (((ds * 4 + q4) ^ fr) * 8)];
#pragma unroll
            for (int ni = 0; ni < 4; ni++)
                accS[ni] = __builtin_amdgcn_mfma_f32_16x16x32_f16(qf[ds], kf[ni], accS[ni], 0, 0, 0);
        }

        // ---- causal mask (diagonal tile only) ----
        if (kt == qt) {
#pragma unroll
            for (int ni = 0; ni < 4; ni++) {
                int kcol = ni * 16 + fr;
#pragma unroll
                for (int r = 0; r < 4; r++) {
                    int qrow = wave * 16 + q4 * 4 + r;
                    if (kcol > qrow) accS[ni][r] = -INFINITY;
                }
            }
        }

        // ---- online softmax ----
#pragma unroll
        for (int r = 0; r < 4; r++) {
            float mold = mrow[r];
            float mx = mold;
#pragma unroll
            for (int ni = 0; ni < 4; ni++) mx = fmaxf(mx, accS[ni][r]);
#pragma unroll
            for (int off = 1; off < 16; off <<= 1)
                mx = fmaxf(mx, __shfl_xor(mx, off));
            float alpha = __expf(mold - mx);
            mrow[r] = mx;
            float rs = 0.f;
#pragma unroll
            for (int ni = 0; ni < 4; ni++) {
                float p = __expf(accS[ni][r] - mx);
                rs += p;
                accS[ni][r] = p;
            }
#pragma unroll
            for (int off = 1; off < 16; off <<= 1)
                rs += __shfl_xor(rs, off);
            lrow[r] = lrow[r] * alpha + rs;
#pragma unroll
            for (int di = 0; di < 8; di++)
                accO[di][r] *= alpha;
        }

        // ---- P -> wave-private scratch (no barrier; intra-wave ordering) ----
#pragma unroll
        for (int ni = 0; ni < 4; ni++)
#pragma unroll
            for (int r = 0; r < 4; r++) {
                float p = accS[ni][r];
                float pp = __shfl_xor(p, 1);
                if ((lane & 1) == 0) {
                    int row = q4 * 4 + r;
                    int col = ni * 16 + fr;                 // even
                    int xc = (col >> 3) ^ (row & 7);
                    __half2 h2;
                    h2.x = __float2half(p);
                    h2.y = __float2half(pp);
                    *(__half2*)&sPw[row * 64 + xc * 8 + (col & 7)] = h2;
                }
            }

        // ---- O += P V ----
#pragma unroll
        for (int ns = 0; ns < 2; ns++) {
            f16x8 pf = *(const f16x8*)&sPw[fr * 64 + (((ns * 4 + q4) ^ (fr & 7)) * 8)];
#pragma unroll
            for (int di = 0; di < 8; di++) {
                f16x8 vf = *(const f16x8*)&sV[(di * 16 + fr) * 64 + (((ns * 4 + q4) ^ (fr & 7)) * 8)];
                accO[di] = __builtin_amdgcn_mfma_f32_16x16x32_f16(pf, vf, accO[di], 0, 0, 0);
            }
        }
        // no barrier here: next iteration's barrier A protects sK/sV
    }

    // ---- epilogue ----
    float linv[4];
#pragma unroll
    for (int r = 0; r < 4; r++) linv[r] = 1.f / lrow[r];

#pragma unroll
    for (int di = 0; di < 8; di++)
#pragma unroll
        for (int r = 0; r < 4; r++) {
            float o = accO[di][r] * linv[r];
            float po = __shfl_xor(o, 1);
            if ((lane & 1) == 0) {
                int srow = qt * 64 + wave * 16 + q4 * 4 + r;
                int d = di * 16 + fr;  // even
                size_t off = ((size_t)(b * SEQ + srow)) * EMB + h * HD + d;
                __half2 h2;
                h2.x = __float2half(o);
                h2.y = __float2half(po);
                *(__half2*)&CTX[off] = h2;
            }
        }
}

// ---------------- output projection: out(fp32) = CTX * Wo^T ----------------
__global__ __launch_bounds__(256) void gemm_out(const __half* __restrict__ CTX,
                                                const __half* __restrict__ Wo,
                                                float* __restrict__ out) {
    __shared__ short sA[128 * 32];
    __shared__ short sB[128 * 32];
    f32x4 z = {0.f, 0.f, 0.f, 0.f};
    f32x4 acc[4][4];
#pragma unroll
    for (int i = 0; i < 4; i++)
#pragma unroll
        for (int j = 0; j < 4; j++) acc[i][j] = z;

    gemm_mainloop(CTX, Wo, blockIdx.x * 128, blockIdx.y * 128, sA, sB, acc);

    const int lane = threadIdx.x & 63;
    const int wave = threadIdx.x >> 6;
    const int wr = wave >> 1, wc = wave & 1;
    const int q4 = lane >> 4;
#pragma unroll
    for (int mi = 0; mi < 4; mi++)
#pragma unroll
        for (int ni = 0; ni < 4; ni++)
#pragma unroll
            for (int r = 0; r < 4; r++) {
                int m = blockIdx.x * 128 + wr * 64 + mi * 16 + q4 * 4 + r;
                int n = blockIdx.y * 128 + wc * 64 + ni * 16 + (lane & 15);
                out[(size_t)m * EMB + n] = acc[mi][ni][r];
            }
}

extern "C" void kernel_launch(void* const* d_in, const int* in_sizes, int n_in,
                              void* d_out, int out_size, void* d_ws, size_t ws_size,
                              hipStream_t stream) {
    const float* x  = (const float*)d_in[0];
    const float* Wq = (const float*)d_in[1];
    const float* Wk = (const float*)d_in[2];
    const float* Wv = (const float*)d_in[3];
    const float* Wo = (const float*)d_in[4];
    float* out = (float*)d_out;

    char* ws = (char*)d_ws;
    size_t off = 0;
    const size_t QKV_ELEMS = (size_t)MROWS * EMB;   // 16777216
    __half* Xh  = (__half*)(ws + off); off += QKV_ELEMS * 2;          // reused as CTX
    __half* Wqh = (__half*)(ws + off); off += (size_t)EMB * EMB * 2;
    __half* Wkh = (__half*)(ws + off); off += (size_t)EMB * EMB * 2;
    __half* Wvh = (__half*)(ws + off); off += (size_t)EMB * EMB * 2;
    __half* Woh = (__half*)(ws + off); off += (size_t)EMB * EMB * 2;
    __half* Qb  = (__half*)(ws + off); off += QKV_ELEMS * 2;
    __half* Kb  = (__half*)(ws + off); off += QKV_ELEMS * 2;
    __half* Vb  = (__half*)(ws + off); off += QKV_ELEMS * 2;
    __half* Vtb = (__half*)(ws + off); off += QKV_ELEMS * 2;
    __half* Cb  = Xh;   // X dead after gemm_qkv

    cvt_f32_f16<<<16384, 256, 0, stream>>>(x,  Xh,  4194304);
    cvt_f32_f16<<<4096,  256, 0, stream>>>(Wq, Wqh, 1048576);
    cvt_f32_f16<<<4096,  256, 0, stream>>>(Wk, Wkh, 1048576);
    cvt_f32_f16<<<4096,  256, 0, stream>>>(Wv, Wvh, 1048576);
    cvt_f32_f16<<<4096,  256, 0, stream>>>(Wo, Woh, 1048576);

    gemm_qkv<<<dim3(64, 48), 256, 0, stream>>>(Xh, Wqh, Wkh, Wvh, Qb, Kb, Vb);
    transpose_v<<<dim3(64, 64), 256, 0, stream>>>(Vb, Vtb);
    attn_kernel<<<dim3(32, 64), 256, 0, stream>>>(Qb, Kb, Vtb, Cb);
    gemm_out<<<dim3(64, 16), 256, 0, stream>>>(Cb, Woh, out);
}